// Round 2
// baseline (4214.128 us; speedup 1.0000x reference)
//
#include <hip/hip_runtime.h>
#include <math.h>

#define C_CH 54
#define CP   64      // candidate row stride: [0..53]=cand, 54=candsq, 55=tcand, 56=libmean
#define NT   20
#define NM   6
#define NK   120     // NM * NT
#define BLK  256
#define PPT  2                     // pixels per thread
#define PIX_PER_BLK (BLK * PPT)    // 512

typedef float f4 __attribute__((ext_vector_type(4)));

// ---------------- prep: candidate table (CP=64 rows) into workspace ----------------
__global__ __launch_bounds__(256) void hadar_prep(
    const float* __restrict__ s_sky, const float* __restrict__ s_ground,
    const float* __restrict__ library, const float* __restrict__ wg,
    float* __restrict__ cand)
{
    __shared__ float xamb[C_CH];
    __shared__ float tc[NT];
    __shared__ float lm[NM];
    const int tid = threadIdx.x;
    if (tid < NT) tc[tid] = 250.0f + (float)tid * (100.0f / 19.0f);
    if (tid < C_CH) xamb[tid] = 0.5f * s_sky[tid] + 0.5f * s_ground[tid];
    if (tid < NM) {
        float s = 0.0f;
        for (int c = 0; c < C_CH; ++c) s += library[tid * C_CH + c];
        lm[tid] = s / (float)C_CH;
    }
    __syncthreads();

    const float c1 = 1.191042e-8f, c2 = 1.4387752f;
    for (int idx = tid; idx < NK * CP; idx += 256) {
        const int k = idx >> 6, c = idx & 63;
        float v = 0.0f;
        if (c < C_CH) {
            const int m = k / NT, t = k - m * NT;
            const float nu = wg[c];
            const float B = c1 * nu * nu * nu / expm1f(c2 * nu / tc[t]);
            const float e = library[m * C_CH + c];
            v = e * B + (1.0f - e) * xamb[c];
        }
        cand[idx] = v;
    }
    __syncthreads();

    if (tid < NK) {
        float s = 0.0f;
        for (int c = 0; c < C_CH; ++c) { float v = cand[tid * CP + c]; s += v * v; }
        const int m = tid / NT, t = tid - m * NT;
        cand[tid * CP + 54] = s;        // candsq
        cand[tid * CP + 55] = tc[t];    // best_t value for this k
        cand[tid * CP + 56] = lm[m];    // texture value for this k
    }
}

// ---------------- main: 2 pixels/thread; candidate rows via PIPELINED wave-uniform
// VMEM broadcast loads. Why not SMEM: s_load returns out-of-order (only lgkmcnt(0)
// is legal) and the 102-SGPR/wave file can't double-buffer a 56-float row, so the
// scalar path serializes at full miss latency (~900 cyc/iter observed, VALUBusy 43-62%).
// global_load with identical address across lanes is 1 transaction + broadcast, returns
// IN ORDER, so counted vmcnt(N) gives a true 3-stage half-row pipeline: issue-to-wait
// distance = 2 halves (~300 cyc) covers L2-hit latency inside a single wave.
// Buffers: 3 x 7 x dwordx4 (84 VGPRs) + 108 row VGPRs -> launch_bounds(256,2) caps
// VGPR at 256 so nothing spills (round-1 lesson: default cap of 64 spilled row1).
#define ISSUE(B, BASE) asm volatile( \
    "global_load_dwordx4 %0, %7, %8 offset:%c9\n\t"  \
    "global_load_dwordx4 %1, %7, %8 offset:%c10\n\t" \
    "global_load_dwordx4 %2, %7, %8 offset:%c11\n\t" \
    "global_load_dwordx4 %3, %7, %8 offset:%c12\n\t" \
    "global_load_dwordx4 %4, %7, %8 offset:%c13\n\t" \
    "global_load_dwordx4 %5, %7, %8 offset:%c14\n\t" \
    "global_load_dwordx4 %6, %7, %8 offset:%c15"     \
    : "=v"(B[0]), "=v"(B[1]), "=v"(B[2]), "=v"(B[3]), "=v"(B[4]), "=v"(B[5]), "=v"(B[6]) \
    : "v"(vz), "s"(cp), \
      "i"(BASE), "i"((BASE)+16), "i"((BASE)+32), "i"((BASE)+48), \
      "i"((BASE)+64), "i"((BASE)+80), "i"((BASE)+96))

// wait until <=N VMEM ops outstanding; tie buffer regs so consumers can't hoist
#define WAITB(N, B) asm volatile("s_waitcnt vmcnt(" #N ")" \
    : "+v"(B[0]), "+v"(B[1]), "+v"(B[2]), "+v"(B[3]), "+v"(B[4]), "+v"(B[5]), "+v"(B[6]))

// half-row FMAs, channels CB..CB+27 (CB=28 half also carries candsq at B[6][2]).
// Accumulation order identical to prior passing kernels: a[c&3] += row[c]*cand[c], c ascending.
#define FMAH(B, CB) { \
    _Pragma("unroll") for (int j = 0; j < 7; ++j) { \
        _Pragma("unroll") for (int e = 0; e < 4; ++e) { \
            const int c = (CB) + 4 * j + e; \
            if (c < C_CH) { \
                const float ce = B[j][e]; \
                a0[c & 3] += row0[c] * ce; \
                a1[c & 3] += row1[c] * ce; \
            } } } }

#define ROWFIN(B, K) { \
    const float sq = B[6][2]; \
    const float d0 = (a0[0] + a0[1]) + (a0[2] + a0[3]); \
    const float d1 = (a1[0] + a1[1]) + (a1[2] + a1[3]); \
    const float l0 = (ssq0 - 2.0f * d0) + sq; \
    const float l1 = (ssq1 - 2.0f * d1) + sq; \
    const bool c0 = l0 < bl0; bl0 = c0 ? l0 : bl0; bk0 = c0 ? (K) : bk0; \
    const bool c1 = l1 < bl1; bl1 = c1 ? l1 : bl1; bk1 = c1 ? (K) : bk1; \
    a0[0] = a0[1] = a0[2] = a0[3] = 0.0f; \
    a1[0] = a1[1] = a1[2] = a1[3] = 0.0f; }

__global__ __launch_bounds__(BLK, 2) void hadar_main(
    const float* __restrict__ s_obs,
    const float* __restrict__ library,
    const float* __restrict__ cand,
    float* __restrict__ out, float* __restrict__ partials, int N)
{
    const int tid = threadIdx.x;
    const long long base = (long long)blockIdx.x * PIX_PER_BLK;
    const long long n0 = base + tid;
    const long long n1 = base + BLK + tid;
    const bool v0 = (n0 < N);
    const bool v1 = (n1 < N);

    // pixel rows in VGPRs (2 x 54 floats); float2 loads keep 8B alignment (row = 216B)
    float row0[C_CH], row1[C_CH];
    if (v0) {
        const float2* rp = (const float2*)(s_obs + n0 * C_CH);
        #pragma unroll
        for (int i = 0; i < C_CH / 2; ++i) {
            float2 w = rp[i];
            row0[2 * i] = w.x; row0[2 * i + 1] = w.y;
        }
    } else {
        #pragma unroll
        for (int c = 0; c < C_CH; ++c) row0[c] = 0.0f;
    }
    if (v1) {
        const float2* rp = (const float2*)(s_obs + n1 * C_CH);
        #pragma unroll
        for (int i = 0; i < C_CH / 2; ++i) {
            float2 w = rp[i];
            row1[2 * i] = w.x; row1[2 * i + 1] = w.y;
        }
    } else {
        #pragma unroll
        for (int c = 0; c < C_CH; ++c) row1[c] = 0.0f;
    }

    // ssq (consumes row loads BEFORE prefetch issue so the compiler's own vmcnt
    // wait for rows lands ahead of our counted pipeline)
    float ssq0 = 0.0f, ssq1 = 0.0f;
    #pragma unroll
    for (int c = 0; c < C_CH; ++c) ssq0 += row0[c] * row0[c];
    #pragma unroll
    for (int c = 0; c < C_CH; ++c) ssq1 += row1[c] * row1[c];

    float bl0 = 3.4e38f, bl1 = 3.4e38f;
    int bk0 = NK, bk1 = NK;
    float a0[4] = {0.f, 0.f, 0.f, 0.f};
    float a1[4] = {0.f, 0.f, 0.f, 0.f};

    // half-row layout: row r -> bytes r*256 (H0: ch 0-27) and r*256+112 (H1: ch 28-55)
    f4 B0[7], B1[7], B2[7];
    int vz = 0;                    // zero voffset VGPR (wave-uniform broadcast loads)
    const float* cp = cand;        // SGPR base, advanced 3 rows (768B) per macro-iter

    // prologue: halves h0,h1,h2 = row0-H0, row0-H1, row1-H0  (21 loads outstanding)
    ISSUE(B0, 0);
    ISSUE(B1, 112);
    ISSUE(B2, 256);

    // steady state: rows R,R+1,R+2 per macro-iter; each slot waits oldest half,
    // computes 28ch x 2px, issues the half 2 ahead. 39 iterations (rows 0..116).
    #pragma unroll 1
    for (int R = 0; R < 117; R += 3) {
        WAITB(14, B0); FMAH(B0, 0);                     ISSUE(B0, 368);   // R+1 H1
        WAITB(14, B1); FMAH(B1, 28); ROWFIN(B1, R);     ISSUE(B1, 512);   // R+2 H0
        WAITB(14, B2); FMAH(B2, 0);                     ISSUE(B2, 624);   // R+2 H1
        WAITB(14, B0); FMAH(B0, 28); ROWFIN(B0, R + 1); ISSUE(B0, 768);   // R+3 H0
        WAITB(14, B1); FMAH(B1, 0);                     ISSUE(B1, 880);   // R+3 H1
        WAITB(14, B2); FMAH(B2, 28); ROWFIN(B2, R + 2); ISSUE(B2, 1024);  // R+4 H0
        cp += 3 * CP;
    }
    // peeled tail R=117 (rows 117-119): issue only the 3 remaining real halves, drain.
    WAITB(14, B0); FMAH(B0, 0);                      ISSUE(B0, 368);  // 118 H1
    WAITB(14, B1); FMAH(B1, 28); ROWFIN(B1, 117);    ISSUE(B1, 512);  // 119 H0
    WAITB(14, B2); FMAH(B2, 0);                      ISSUE(B2, 624);  // 119 H1
    WAITB(14, B0); FMAH(B0, 28); ROWFIN(B0, 118);
    WAITB(7,  B1); FMAH(B1, 0);
    WAITB(0,  B2); FMAH(B2, 28); ROWFIN(B2, 119);

    // clamp invalid pixels so table indexing below stays in-bounds
    if (!v0) bk0 = 0;
    if (!v1) bk1 = 0;

    const size_t NN = (size_t)N;
    const size_t NC = (size_t)C_CH * NN;

    // ---- small per-pixel outputs (coalesced) ----
    if (v0) {
        const float* cr = cand + (size_t)bk0 * CP;
        out[n0] = cr[55];                      // best_t
        out[NN + NC + n0] = 0.5f;              // best_v
        out[2 * NN + NC + n0] = 0.0f;          // beta
        out[3 * NN + NC + n0] = cr[56];        // texture
    }
    if (v1) {
        const float* cr = cand + (size_t)bk1 * CP;
        out[n1] = cr[55];
        out[NN + NC + n1] = 0.5f;
        out[2 * NN + NC + n1] = 0.0f;
        out[3 * NN + NC + n1] = cr[56];
    }

    // ---- block-coalesced writer for best_e and s_recon ----
    __shared__ int2 bkm[PIX_PER_BLK];   // {cand row offset, library row offset}
    bkm[tid]       = make_int2(bk0 * CP, (bk0 / NT) * C_CH);
    bkm[tid + BLK] = make_int2(bk1 * CP, (bk1 / NT) * C_CH);

    float lsum = (v0 ? bl0 : 0.0f) + (v1 ? bl1 : 0.0f);
    __syncthreads();

    {
        float* __restrict__ be = out + NN + (size_t)base * C_CH;
        float* __restrict__ sr = out + 4 * NN + NC + (size_t)base * C_CH;
        int p = tid / C_CH;
        int c = tid - p * C_CH;
        #pragma unroll 4
        for (int j = tid; j < PIX_PER_BLK * C_CH; j += BLK) {   // 108 iterations
            const int2 o = bkm[p];
            const float ev = library[o.y + c];   // L1-resident (1.3 KB)
            const float sv = cand[o.x + c];      // L1/L2-resident (30 KB)
            if (base + p < N) { be[j] = ev; sr[j] = sv; }
            p += 4; c += 40;
            if (c >= C_CH) { c -= C_CH; ++p; }
        }
    }

    // ---- deterministic block reduction of best_loss sum ----
    __shared__ float red[BLK];
    red[tid] = lsum;
    __syncthreads();
    #pragma unroll
    for (int s = BLK / 2; s > 0; s >>= 1) {
        if (tid < s) red[tid] += red[tid + s];
        __syncthreads();
    }
    if (tid == 0) partials[blockIdx.x] = red[0];
}

// ---------------- final reduce: objective = mean(best_loss) ----------------
__global__ __launch_bounds__(256) void hadar_reduce(
    const float* __restrict__ partials, int nb, float* __restrict__ obj_out, float invN)
{
    __shared__ float red[256];
    float s = 0.0f;
    for (int i = threadIdx.x; i < nb; i += 256) s += partials[i];
    red[threadIdx.x] = s;
    __syncthreads();
    #pragma unroll
    for (int st = 128; st > 0; st >>= 1) {
        if (threadIdx.x < st) red[threadIdx.x] += red[threadIdx.x + st];
        __syncthreads();
    }
    if (threadIdx.x == 0) *obj_out = red[0] * invN;
}

extern "C" void kernel_launch(void* const* d_in, const int* in_sizes, int n_in,
                              void* d_out, int out_size, void* d_ws, size_t ws_size,
                              hipStream_t stream)
{
    const float* s_obs    = (const float*)d_in[0];
    const float* s_sky    = (const float*)d_in[1];
    const float* s_ground = (const float*)d_in[2];
    const float* library  = (const float*)d_in[3];
    const float* wg       = (const float*)d_in[4];
    float* out = (float*)d_out;

    const int N  = in_sizes[0] / C_CH;
    const int nb = (N + PIX_PER_BLK - 1) / PIX_PER_BLK;

    float* ws       = (float*)d_ws;
    float* cand     = ws;              // NK*CP = 7680 floats
    float* partials = ws + 8192;       // nb floats

    hadar_prep<<<1, 256, 0, stream>>>(s_sky, s_ground, library, wg, cand);
    hadar_main<<<nb, BLK, 0, stream>>>(s_obs, library, cand, out, partials, N);

    const size_t NN = (size_t)N;
    float* obj_out = out + 4 * NN + 2 * (size_t)C_CH * NN;
    hadar_reduce<<<1, 256, 0, stream>>>(partials, nb, obj_out, 1.0f / (float)N);
}

// Round 4
// 1382.593 us; speedup vs baseline: 3.0480x; 3.0480x over previous
//
#include <hip/hip_runtime.h>
#include <math.h>

#define C_CH 54
#define CP   64      // candidate row stride: [0..53]=cand, 54=candsq, 55=tcand, 56=libmean
#define NT   20
#define NM   6
#define NK   120     // NM * NT
#define BLK  256
#define PPT  2                     // pixels per thread
#define PIX_PER_BLK (BLK * PPT)    // 512
#define NF4  (NK * CP / 4)         // 1920 f4 elements in the table

typedef float f4 __attribute__((ext_vector_type(4)));

// ---------------- prep: candidate table (CP=64 rows) into workspace ----------------
__global__ __launch_bounds__(256) void hadar_prep(
    const float* __restrict__ s_sky, const float* __restrict__ s_ground,
    const float* __restrict__ library, const float* __restrict__ wg,
    float* __restrict__ cand)
{
    __shared__ float xamb[C_CH];
    __shared__ float tc[NT];
    __shared__ float lm[NM];
    const int tid = threadIdx.x;
    if (tid < NT) tc[tid] = 250.0f + (float)tid * (100.0f / 19.0f);
    if (tid < C_CH) xamb[tid] = 0.5f * s_sky[tid] + 0.5f * s_ground[tid];
    if (tid < NM) {
        float s = 0.0f;
        for (int c = 0; c < C_CH; ++c) s += library[tid * C_CH + c];
        lm[tid] = s / (float)C_CH;
    }
    __syncthreads();

    const float c1 = 1.191042e-8f, c2 = 1.4387752f;
    for (int idx = tid; idx < NK * CP; idx += 256) {
        const int k = idx >> 6, c = idx & 63;
        float v = 0.0f;
        if (c < C_CH) {
            const int m = k / NT, t = k - m * NT;
            const float nu = wg[c];
            const float B = c1 * nu * nu * nu / expm1f(c2 * nu / tc[t]);
            const float e = library[m * C_CH + c];
            v = e * B + (1.0f - e) * xamb[c];
        }
        cand[idx] = v;
    }
    __syncthreads();

    if (tid < NK) {
        float s = 0.0f;
        for (int c = 0; c < C_CH; ++c) { float v = cand[tid * CP + c]; s += v * v; }
        const int m = tid / NT, t = tid - m * NT;
        cand[tid * CP + 54] = s;        // candsq
        cand[tid * CP + 55] = tc[t];    // best_t value for this k
        cand[tid * CP + 56] = lm[m];    // texture value for this k
    }
}

// ---------------- main: 2 pixels/thread; candidate table staged in LDS ----------------
// Round-2 lesson (FETCH 8.2 GB, VALUBusy 6%, VGPR=128): inline-asm VMEM buffers +
// 108 row floats exceeded the allocator's chosen budget -> pixel rows spilled to
// scratch (= HBM) inside the k-loop. Fix: (a) candidate stream via LDS, where
// same-address reads are a TRUE hardware broadcast (no conflict) and latency is
// ~120 cyc, hidden under 216 cyc of FMA per row by a 2-row ping-pong with STATIC
// indexing (no runtime-indexed arrays -> nothing goes to scratch); (b) pin the
// register budget with amdgpu_waves_per_eu(2,2) so the allocator keeps the ~190
// live floats in VGPRs (256 available at 2 waves/EU) instead of spilling.

#define LOADROW(B, K) { \
    const f4* __restrict__ Lr = Lc + (size_t)(K) * (CP / 4); \
    _Pragma("unroll") for (int j = 0; j < 14; ++j) B[j] = Lr[j]; }

// accumulation order identical to all prior passing kernels:
// a[c&3] += row[c] * cand[c], c ascending; loss = (ssq - 2*dot) + candsq;
// strict '<' with ascending k == first-min.
#define FMAROW(B, K) { \
    float a0[4] = {0.f, 0.f, 0.f, 0.f}; \
    float a1[4] = {0.f, 0.f, 0.f, 0.f}; \
    _Pragma("unroll") for (int j = 0; j < 14; ++j) { \
        _Pragma("unroll") for (int e = 0; e < 4; ++e) { \
            const int c = 4 * j + e; \
            if (c < C_CH) { \
                const float ce = B[j][e]; \
                a0[c & 3] += row0[c] * ce; \
                a1[c & 3] += row1[c] * ce; \
            } } } \
    const float sq = B[13][2]; \
    const float d0 = (a0[0] + a0[1]) + (a0[2] + a0[3]); \
    const float d1 = (a1[0] + a1[1]) + (a1[2] + a1[3]); \
    const float l0 = (ssq0 - 2.0f * d0) + sq; \
    const float l1 = (ssq1 - 2.0f * d1) + sq; \
    const bool c0 = l0 < bl0; bl0 = c0 ? l0 : bl0; bk0 = c0 ? (K) : bk0; \
    const bool c1 = l1 < bl1; bl1 = c1 ? l1 : bl1; bk1 = c1 ? (K) : bk1; }

__global__ __launch_bounds__(BLK)
__attribute__((amdgpu_waves_per_eu(2, 2)))
void hadar_main(
    const float* __restrict__ s_obs,
    const float* __restrict__ library,
    const float* __restrict__ cand,
    float* __restrict__ out, float* __restrict__ partials, int N)
{
    __shared__ f4 ldsc[NF4];            // 30720 B candidate table
    __shared__ int2 bkm[PIX_PER_BLK];   // 4096 B
    __shared__ float red[BLK];          // 1024 B

    const int tid = threadIdx.x;
    const long long base = (long long)blockIdx.x * PIX_PER_BLK;
    const long long n0 = base + tid;
    const long long n1 = base + BLK + tid;
    const bool v0 = (n0 < N);
    const bool v1 = (n1 < N);

    // ---- stage candidate table global -> LDS (coalesced dwordx4) ----
    {
        const f4* __restrict__ gc = (const f4*)cand;
        #pragma unroll
        for (int j = tid; j < NF4; j += BLK) ldsc[j] = gc[j];
    }

    // pixel rows in VGPRs (2 x 54 floats); float2 loads (row stride 216 B = 8B aligned)
    float row0[C_CH], row1[C_CH];
    if (v0) {
        const float2* rp = (const float2*)(s_obs + n0 * C_CH);
        #pragma unroll
        for (int i = 0; i < C_CH / 2; ++i) {
            float2 w = rp[i];
            row0[2 * i] = w.x; row0[2 * i + 1] = w.y;
        }
    } else {
        #pragma unroll
        for (int c = 0; c < C_CH; ++c) row0[c] = 0.0f;
    }
    if (v1) {
        const float2* rp = (const float2*)(s_obs + n1 * C_CH);
        #pragma unroll
        for (int i = 0; i < C_CH / 2; ++i) {
            float2 w = rp[i];
            row1[2 * i] = w.x; row1[2 * i + 1] = w.y;
        }
    } else {
        #pragma unroll
        for (int c = 0; c < C_CH; ++c) row1[c] = 0.0f;
    }

    float ssq0 = 0.0f, ssq1 = 0.0f;
    #pragma unroll
    for (int c = 0; c < C_CH; ++c) ssq0 += row0[c] * row0[c];
    #pragma unroll
    for (int c = 0; c < C_CH; ++c) ssq1 += row1[c] * row1[c];

    float bl0 = 3.4e38f, bl1 = 3.4e38f;
    int bk0 = NK, bk1 = NK;

    __syncthreads();   // table staged

    const f4* __restrict__ Lc = ldsc;

    // ---- k-loop: 2-row ping-pong, static buffers A/B ----
    f4 A[14], B[14];
    LOADROW(A, 0);
    #pragma unroll 1
    for (int k = 0; k < NK - 2; k += 2) {
        LOADROW(B, k + 1);
        FMAROW(A, k);
        LOADROW(A, k + 2);
        FMAROW(B, k + 1);
    }
    LOADROW(B, NK - 1);
    FMAROW(A, NK - 2);
    FMAROW(B, NK - 1);

    // clamp invalid pixels so table indexing below stays in-bounds
    if (!v0) bk0 = 0;
    if (!v1) bk1 = 0;

    const size_t NN = (size_t)N;
    const size_t NC = (size_t)C_CH * NN;
    const float* __restrict__ Lf = (const float*)ldsc;

    // ---- small per-pixel outputs (coalesced; table values from LDS) ----
    if (v0) {
        out[n0] = Lf[bk0 * CP + 55];           // best_t
        out[NN + NC + n0] = 0.5f;              // best_v
        out[2 * NN + NC + n0] = 0.0f;          // beta
        out[3 * NN + NC + n0] = Lf[bk0 * CP + 56];   // texture
    }
    if (v1) {
        out[n1] = Lf[bk1 * CP + 55];
        out[NN + NC + n1] = 0.5f;
        out[2 * NN + NC + n1] = 0.0f;
        out[3 * NN + NC + n1] = Lf[bk1 * CP + 56];
    }

    // ---- block-coalesced writer for best_e and s_recon ----
    bkm[tid]       = make_int2(bk0 * CP, (bk0 / NT) * C_CH);
    bkm[tid + BLK] = make_int2(bk1 * CP, (bk1 / NT) * C_CH);

    float lsum = (v0 ? bl0 : 0.0f) + (v1 ? bl1 : 0.0f);
    __syncthreads();

    {
        float* __restrict__ be = out + NN + (size_t)base * C_CH;
        float* __restrict__ sr = out + 4 * NN + NC + (size_t)base * C_CH;
        int p = tid / C_CH;
        int c = tid - p * C_CH;
        #pragma unroll 4
        for (int j = tid; j < PIX_PER_BLK * C_CH; j += BLK) {   // 108 iterations
            const int2 o = bkm[p];
            const float ev = library[o.y + c];   // L1-resident (1.3 KB)
            const float sv = Lf[o.x + c];        // LDS
            if (base + p < N) { be[j] = ev; sr[j] = sv; }
            p += 4; c += 40;
            if (c >= C_CH) { c -= C_CH; ++p; }
        }
    }

    // ---- deterministic block reduction of best_loss sum ----
    red[tid] = lsum;
    __syncthreads();
    #pragma unroll
    for (int s = BLK / 2; s > 0; s >>= 1) {
        if (tid < s) red[tid] += red[tid + s];
        __syncthreads();
    }
    if (tid == 0) partials[blockIdx.x] = red[0];
}

// ---------------- final reduce: objective = mean(best_loss) ----------------
__global__ __launch_bounds__(256) void hadar_reduce(
    const float* __restrict__ partials, int nb, float* __restrict__ obj_out, float invN)
{
    __shared__ float red[256];
    float s = 0.0f;
    for (int i = threadIdx.x; i < nb; i += 256) s += partials[i];
    red[threadIdx.x] = s;
    __syncthreads();
    #pragma unroll
    for (int st = 128; st > 0; st >>= 1) {
        if (threadIdx.x < st) red[threadIdx.x] += red[threadIdx.x + st];
        __syncthreads();
    }
    if (threadIdx.x == 0) *obj_out = red[0] * invN;
}

extern "C" void kernel_launch(void* const* d_in, const int* in_sizes, int n_in,
                              void* d_out, int out_size, void* d_ws, size_t ws_size,
                              hipStream_t stream)
{
    const float* s_obs    = (const float*)d_in[0];
    const float* s_sky    = (const float*)d_in[1];
    const float* s_ground = (const float*)d_in[2];
    const float* library  = (const float*)d_in[3];
    const float* wg       = (const float*)d_in[4];
    float* out = (float*)d_out;

    const int N  = in_sizes[0] / C_CH;
    const int nb = (N + PIX_PER_BLK - 1) / PIX_PER_BLK;

    float* ws       = (float*)d_ws;
    float* cand     = ws;              // NK*CP = 7680 floats
    float* partials = ws + 8192;       // nb floats

    hadar_prep<<<1, 256, 0, stream>>>(s_sky, s_ground, library, wg, cand);
    hadar_main<<<nb, BLK, 0, stream>>>(s_obs, library, cand, out, partials, N);

    const size_t NN = (size_t)N;
    float* obj_out = out + 4 * NN + 2 * (size_t)C_CH * NN;
    hadar_reduce<<<1, 256, 0, stream>>>(partials, nb, obj_out, 1.0f / (float)N);
}

// Round 5
// 777.383 us; speedup vs baseline: 5.4209x; 1.7785x over previous
//
#include <hip/hip_runtime.h>
#include <math.h>

#define C_CH 54
#define CP   64      // candidate row stride: [0..53]=cand, 54=candsq, 55=tcand, 56=libmean
#define NT   20
#define NM   6
#define NK   120     // NM * NT
#define BLK  256
#define PPT  2                     // pixels per thread
#define PIX_PER_BLK (BLK * PPT)    // 512

typedef float sf16 __attribute__((ext_vector_type(16)));
typedef float sf8  __attribute__((ext_vector_type(8)));

// ---------------- prep: candidate table (CP=64 rows) into workspace ----------------
__global__ __launch_bounds__(256) void hadar_prep(
    const float* __restrict__ s_sky, const float* __restrict__ s_ground,
    const float* __restrict__ library, const float* __restrict__ wg,
    float* __restrict__ cand)
{
    __shared__ float xamb[C_CH];
    __shared__ float tc[NT];
    __shared__ float lm[NM];
    const int tid = threadIdx.x;
    if (tid < NT) tc[tid] = 250.0f + (float)tid * (100.0f / 19.0f);
    if (tid < C_CH) xamb[tid] = 0.5f * s_sky[tid] + 0.5f * s_ground[tid];
    if (tid < NM) {
        float s = 0.0f;
        for (int c = 0; c < C_CH; ++c) s += library[tid * C_CH + c];
        lm[tid] = s / (float)C_CH;
    }
    __syncthreads();

    const float c1 = 1.191042e-8f, c2 = 1.4387752f;
    for (int idx = tid; idx < NK * CP; idx += 256) {
        const int k = idx >> 6, c = idx & 63;
        float v = 0.0f;
        if (c < C_CH) {
            const int m = k / NT, t = k - m * NT;
            const float nu = wg[c];
            const float B = c1 * nu * nu * nu / expm1f(c2 * nu / tc[t]);
            const float e = library[m * C_CH + c];
            v = e * B + (1.0f - e) * xamb[c];
        }
        cand[idx] = v;
    }
    __syncthreads();

    if (tid < NK) {
        float s = 0.0f;
        for (int c = 0; c < C_CH; ++c) { float v = cand[tid * CP + c]; s += v * v; }
        const int m = tid / NT, t = tid - m * NT;
        cand[tid * CP + 54] = s;        // candsq
        cand[tid * CP + 55] = tc[t];    // best_t value for this k
        cand[tid * CP + 56] = lm[m];    // texture value for this k
    }
}

// element c of the current candidate row held in SGPRs (c is compile-time after unroll)
#define CE(c) ((c) < 16 ? q0[(c)] : (c) < 32 ? q1[(c)-16] : (c) < 48 ? q2[(c)-32] : q3[(c)-48])

// ---------------- main: TWO pixels per thread, candidate rows via scalar loads ----------
// Round-1 structure, with the register budget actually granted this time:
// __launch_bounds__(256, 4) -> 512/4 = 128 VGPR budget. Live set = 108 row floats
// + 8 accumulators + temps ~= 122 <= 128, so nothing spills (round-1's identical
// code at the default 64-VGPR target spilled row1 and ate the 2x amortization;
// rounds 2/4 proved the allocator WILL use up to 128). Candidate row stays in
// SGPRs (s_load path) -> zero VGPR pressure from the table stream. 4 resident
// waves/SIMD cover the per-iteration SMEM latency (~250-400 cyc) over 240 cyc
// of FMA work.
__global__ __launch_bounds__(BLK, 4) void hadar_main(
    const float* __restrict__ s_obs,
    const float* __restrict__ library,
    const float* __restrict__ cand,
    float* __restrict__ out, float* __restrict__ partials, int N)
{
    const int tid = threadIdx.x;
    const long long base = (long long)blockIdx.x * PIX_PER_BLK;
    const long long n0 = base + tid;
    const long long n1 = base + BLK + tid;
    const bool v0 = (n0 < N);
    const bool v1 = (n1 < N);

    // pixel rows in VGPRs (2 x 54 floats)
    float row0[C_CH], row1[C_CH];
    if (v0) {
        const float2* rp = (const float2*)(s_obs + n0 * C_CH);
        #pragma unroll
        for (int i = 0; i < C_CH / 2; ++i) {
            float2 w = rp[i];
            row0[2 * i] = w.x; row0[2 * i + 1] = w.y;
        }
    } else {
        #pragma unroll
        for (int c = 0; c < C_CH; ++c) row0[c] = 0.0f;
    }
    if (v1) {
        const float2* rp = (const float2*)(s_obs + n1 * C_CH);
        #pragma unroll
        for (int i = 0; i < C_CH / 2; ++i) {
            float2 w = rp[i];
            row1[2 * i] = w.x; row1[2 * i + 1] = w.y;
        }
    } else {
        #pragma unroll
        for (int c = 0; c < C_CH; ++c) row1[c] = 0.0f;
    }

    // ssq, same sequential order as before
    float ssq0 = 0.0f, ssq1 = 0.0f;
    #pragma unroll
    for (int c = 0; c < C_CH; ++c) ssq0 += row0[c] * row0[c];
    #pragma unroll
    for (int c = 0; c < C_CH; ++c) ssq1 += row1[c] * row1[c];

    float bl0 = 3.4e38f, bl1 = 3.4e38f;
    int bk0 = NK, bk1 = NK;   // sentinel larger than any real k

    // per-wave rotation: 15 distinct starts, step 8 (15*8 = 120).
    const int wid = __builtin_amdgcn_readfirstlane(tid >> 6);
    const int rot = (int)((blockIdx.x * 4u + (unsigned)wid) % 15u) * 8;

    int kk = rot;
    const float* pk = cand + (size_t)rot * CP;
    #pragma unroll 1
    for (int i = 0; i < NK; ++i) {
        sf16 q0, q1, q2;
        sf8  q3;
        asm volatile("s_load_dwordx16 %0, %1, 0x0"  : "=s"(q0) : "s"(pk));
        asm volatile("s_load_dwordx16 %0, %1, 0x40" : "=s"(q1) : "s"(pk));
        asm volatile("s_load_dwordx16 %0, %1, 0x80" : "=s"(q2) : "s"(pk));
        asm volatile("s_load_dwordx8  %0, %1, 0xc0" : "=s"(q3) : "s"(pk));
        // tie the wait to the loaded values so consumers can't be hoisted above it
        asm volatile("s_waitcnt lgkmcnt(0)" : "+s"(q0), "+s"(q1), "+s"(q2), "+s"(q3));

        float a0[4] = {0.f, 0.f, 0.f, 0.f};
        float a1[4] = {0.f, 0.f, 0.f, 0.f};
        #pragma unroll
        for (int c = 0; c < C_CH; ++c) {
            const float ce = CE(c);
            a0[c & 3] += row0[c] * ce;
            a1[c & 3] += row1[c] * ce;
        }
        const float sq = q3[6];   // slot 54 = candsq
        const float d0 = (a0[0] + a0[1]) + (a0[2] + a0[3]);
        const float d1 = (a1[0] + a1[1]) + (a1[2] + a1[3]);
        const float l0 = (ssq0 - 2.0f * d0) + sq;
        const float l1 = (ssq1 - 2.0f * d1) + sq;
        // lexicographic (loss, k) min == first-min in k order
        if (l0 < bl0 || (l0 == bl0 && kk < bk0)) { bl0 = l0; bk0 = kk; }
        if (l1 < bl1 || (l1 == bl1 && kk < bk1)) { bl1 = l1; bk1 = kk; }

        ++kk; pk += CP;
        if (kk == NK) { kk = 0; pk = cand; }
    }

    // clamp invalid pixels so table indexing below stays in-bounds
    if (!v0) bk0 = 0;
    if (!v1) bk1 = 0;

    const size_t NN = (size_t)N;
    const size_t NC = (size_t)C_CH * NN;

    // ---- small per-pixel outputs (coalesced) ----
    if (v0) {
        const float* cr = cand + (size_t)bk0 * CP;
        out[n0] = cr[55];                      // best_t
        out[NN + NC + n0] = 0.5f;              // best_v
        out[2 * NN + NC + n0] = 0.0f;          // beta
        out[3 * NN + NC + n0] = cr[56];        // texture
    }
    if (v1) {
        const float* cr = cand + (size_t)bk1 * CP;
        out[n1] = cr[55];
        out[NN + NC + n1] = 0.5f;
        out[2 * NN + NC + n1] = 0.0f;
        out[3 * NN + NC + n1] = cr[56];
    }

    // ---- block-coalesced writer for best_e and s_recon ----
    __shared__ int2 bkm[PIX_PER_BLK];   // {cand row offset, library row offset}
    bkm[tid]       = make_int2(bk0 * CP, (bk0 / NT) * C_CH);
    bkm[tid + BLK] = make_int2(bk1 * CP, (bk1 / NT) * C_CH);

    float lsum = (v0 ? bl0 : 0.0f) + (v1 ? bl1 : 0.0f);
    __syncthreads();

    {
        float* __restrict__ be = out + NN + (size_t)base * C_CH;
        float* __restrict__ sr = out + 4 * NN + NC + (size_t)base * C_CH;
        int p = tid / C_CH;
        int c = tid - p * C_CH;
        #pragma unroll 4
        for (int j = tid; j < PIX_PER_BLK * C_CH; j += BLK) {   // 108 iterations
            const int2 o = bkm[p];
            const float ev = library[o.y + c];   // L1-resident (1.3 KB)
            const float sv = cand[o.x + c];      // L1/L2-resident (30 KB)
            if (base + p < N) { be[j] = ev; sr[j] = sv; }
            p += 4; c += 40;
            if (c >= C_CH) { c -= C_CH; ++p; }
        }
    }

    // ---- deterministic block reduction of best_loss sum ----
    __shared__ float red[BLK];
    red[tid] = lsum;
    __syncthreads();
    #pragma unroll
    for (int s = BLK / 2; s > 0; s >>= 1) {
        if (tid < s) red[tid] += red[tid + s];
        __syncthreads();
    }
    if (tid == 0) partials[blockIdx.x] = red[0];
}

// ---------------- final reduce: objective = mean(best_loss) ----------------
__global__ __launch_bounds__(256) void hadar_reduce(
    const float* __restrict__ partials, int nb, float* __restrict__ obj_out, float invN)
{
    __shared__ float red[256];
    float s = 0.0f;
    for (int i = threadIdx.x; i < nb; i += 256) s += partials[i];
    red[threadIdx.x] = s;
    __syncthreads();
    #pragma unroll
    for (int st = 128; st > 0; st >>= 1) {
        if (threadIdx.x < st) red[threadIdx.x] += red[threadIdx.x + st];
        __syncthreads();
    }
    if (threadIdx.x == 0) *obj_out = red[0] * invN;
}

extern "C" void kernel_launch(void* const* d_in, const int* in_sizes, int n_in,
                              void* d_out, int out_size, void* d_ws, size_t ws_size,
                              hipStream_t stream)
{
    const float* s_obs    = (const float*)d_in[0];
    const float* s_sky    = (const float*)d_in[1];
    const float* s_ground = (const float*)d_in[2];
    const float* library  = (const float*)d_in[3];
    const float* wg       = (const float*)d_in[4];
    float* out = (float*)d_out;

    const int N  = in_sizes[0] / C_CH;
    const int nb = (N + PIX_PER_BLK - 1) / PIX_PER_BLK;

    float* ws       = (float*)d_ws;
    float* cand     = ws;              // NK*CP = 7680 floats
    float* partials = ws + 8192;       // nb floats

    hadar_prep<<<1, 256, 0, stream>>>(s_sky, s_ground, library, wg, cand);
    hadar_main<<<nb, BLK, 0, stream>>>(s_obs, library, cand, out, partials, N);

    const size_t NN = (size_t)N;
    float* obj_out = out + 4 * NN + 2 * (size_t)C_CH * NN;
    hadar_reduce<<<1, 256, 0, stream>>>(partials, nb, obj_out, 1.0f / (float)N);
}

// Round 10
// 776.823 us; speedup vs baseline: 5.4248x; 1.0007x over previous
//
#include <hip/hip_runtime.h>
#include <math.h>

#define C_CH 54
#define CP   64      // candidate row stride: [0..53]=cand, 54=candsq, 55=tcand, 56=libmean
#define NT   20
#define NM   6
#define NK   120     // NM * NT
#define BLK  256
#define PPT  2                     // pixels per thread
#define PIX_PER_BLK (BLK * PPT)    // 512

typedef float sf16 __attribute__((ext_vector_type(16)));
typedef float sf8  __attribute__((ext_vector_type(8)));

// ---------------- prep: candidate table (CP=64 rows) into workspace ----------------
__global__ __launch_bounds__(256) void hadar_prep(
    const float* __restrict__ s_sky, const float* __restrict__ s_ground,
    const float* __restrict__ library, const float* __restrict__ wg,
    float* __restrict__ cand)
{
    __shared__ float xamb[C_CH];
    __shared__ float tc[NT];
    __shared__ float lm[NM];
    const int tid = threadIdx.x;
    if (tid < NT) tc[tid] = 250.0f + (float)tid * (100.0f / 19.0f);
    if (tid < C_CH) xamb[tid] = 0.5f * s_sky[tid] + 0.5f * s_ground[tid];
    if (tid < NM) {
        float s = 0.0f;
        for (int c = 0; c < C_CH; ++c) s += library[tid * C_CH + c];
        lm[tid] = s / (float)C_CH;
    }
    __syncthreads();

    const float c1 = 1.191042e-8f, c2 = 1.4387752f;
    for (int idx = tid; idx < NK * CP; idx += 256) {
        const int k = idx >> 6, c = idx & 63;
        float v = 0.0f;
        if (c < C_CH) {
            const int m = k / NT, t = k - m * NT;
            const float nu = wg[c];
            const float B = c1 * nu * nu * nu / expm1f(c2 * nu / tc[t]);
            const float e = library[m * C_CH + c];
            v = e * B + (1.0f - e) * xamb[c];
        }
        cand[idx] = v;
    }
    __syncthreads();

    if (tid < NK) {
        float s = 0.0f;
        for (int c = 0; c < C_CH; ++c) { float v = cand[tid * CP + c]; s += v * v; }
        const int m = tid / NT, t = tid - m * NT;
        cand[tid * CP + 54] = s;        // candsq
        cand[tid * CP + 55] = tc[t];    // best_t value for this k
        cand[tid * CP + 56] = lm[m];    // texture value for this k
    }
}

// element c of the current candidate row held in SGPRs (c is compile-time after unroll)
#define CE(c) ((c) < 16 ? q0[(c)] : (c) < 32 ? q1[(c)-16] : (c) < 48 ? q2[(c)-32] : q3[(c)-48])

// ---------------- main: TWO pixels per thread, candidate rows via scalar loads ----------
// ROUND-9 LESSON: the loss MUST be computed against the exact cand[] values with
// the exact accumulation pattern of the proven kernels (a[c&3] += row[c]*ce,
// l=(ssq-2d)+sq, lexicographic tie-break). A factored-table variant (algebraically
// identical, different rounding) flipped argmins by up to 11 t-steps on
// low-emissivity pixels whose loss-in-t curve is nearly flat. absmax margin is
// one tie-flip wide (6.0 vs threshold 7.0) -- do not perturb this arithmetic.
//
// ROUND-5 LESSON: at the allocator's default 64-VGPR target the ~122-float live
// set is shuffled through AGPRs (unified file: no scratch traffic, but +66us of
// v_accvgpr_read/write VALU overhead). __launch_bounds__(,4) did NOT move the
// allocator; amdgpu_waves_per_eu DID in rounds 2/4. (4,4) sets the budget to
// exactly 512/4 = 128 >= 122 live -> row0+row1 stay in architectural VGPRs,
// the 2x wait-amortization of PPT=2 becomes pure win.
__global__ __launch_bounds__(BLK)
__attribute__((amdgpu_waves_per_eu(4, 4)))
void hadar_main(
    const float* __restrict__ s_obs,
    const float* __restrict__ library,
    const float* __restrict__ cand,
    float* __restrict__ out, float* __restrict__ partials, int N)
{
    const int tid = threadIdx.x;
    const long long base = (long long)blockIdx.x * PIX_PER_BLK;
    const long long n0 = base + tid;
    const long long n1 = base + BLK + tid;
    const bool v0 = (n0 < N);
    const bool v1 = (n1 < N);

    // pixel rows in VGPRs (2 x 54 floats)
    float row0[C_CH], row1[C_CH];
    if (v0) {
        const float2* rp = (const float2*)(s_obs + n0 * C_CH);
        #pragma unroll
        for (int i = 0; i < C_CH / 2; ++i) {
            float2 w = rp[i];
            row0[2 * i] = w.x; row0[2 * i + 1] = w.y;
        }
    } else {
        #pragma unroll
        for (int c = 0; c < C_CH; ++c) row0[c] = 0.0f;
    }
    if (v1) {
        const float2* rp = (const float2*)(s_obs + n1 * C_CH);
        #pragma unroll
        for (int i = 0; i < C_CH / 2; ++i) {
            float2 w = rp[i];
            row1[2 * i] = w.x; row1[2 * i + 1] = w.y;
        }
    } else {
        #pragma unroll
        for (int c = 0; c < C_CH; ++c) row1[c] = 0.0f;
    }

    // ssq, same sequential order as before
    float ssq0 = 0.0f, ssq1 = 0.0f;
    #pragma unroll
    for (int c = 0; c < C_CH; ++c) ssq0 += row0[c] * row0[c];
    #pragma unroll
    for (int c = 0; c < C_CH; ++c) ssq1 += row1[c] * row1[c];

    float bl0 = 3.4e38f, bl1 = 3.4e38f;
    int bk0 = NK, bk1 = NK;   // sentinel larger than any real k

    // per-wave rotation: 15 distinct starts, step 8 (15*8 = 120).
    const int wid = __builtin_amdgcn_readfirstlane(tid >> 6);
    const int rot = (int)((blockIdx.x * 4u + (unsigned)wid) % 15u) * 8;

    int kk = rot;
    const float* pk = cand + (size_t)rot * CP;
    #pragma unroll 1
    for (int i = 0; i < NK; ++i) {
        sf16 q0, q1, q2;
        sf8  q3;
        asm volatile("s_load_dwordx16 %0, %1, 0x0"  : "=s"(q0) : "s"(pk));
        asm volatile("s_load_dwordx16 %0, %1, 0x40" : "=s"(q1) : "s"(pk));
        asm volatile("s_load_dwordx16 %0, %1, 0x80" : "=s"(q2) : "s"(pk));
        asm volatile("s_load_dwordx8  %0, %1, 0xc0" : "=s"(q3) : "s"(pk));
        // tie the wait to the loaded values so consumers can't be hoisted above it
        asm volatile("s_waitcnt lgkmcnt(0)" : "+s"(q0), "+s"(q1), "+s"(q2), "+s"(q3));

        float a0[4] = {0.f, 0.f, 0.f, 0.f};
        float a1[4] = {0.f, 0.f, 0.f, 0.f};
        #pragma unroll
        for (int c = 0; c < C_CH; ++c) {
            const float ce = CE(c);
            a0[c & 3] += row0[c] * ce;
            a1[c & 3] += row1[c] * ce;
        }
        const float sq = q3[6];   // slot 54 = candsq
        const float d0 = (a0[0] + a0[1]) + (a0[2] + a0[3]);
        const float d1 = (a1[0] + a1[1]) + (a1[2] + a1[3]);
        const float l0 = (ssq0 - 2.0f * d0) + sq;
        const float l1 = (ssq1 - 2.0f * d1) + sq;
        // lexicographic (loss, k) min == first-min in k order
        if (l0 < bl0 || (l0 == bl0 && kk < bk0)) { bl0 = l0; bk0 = kk; }
        if (l1 < bl1 || (l1 == bl1 && kk < bk1)) { bl1 = l1; bk1 = kk; }

        ++kk; pk += CP;
        if (kk == NK) { kk = 0; pk = cand; }
    }

    // clamp invalid pixels so table indexing below stays in-bounds
    if (!v0) bk0 = 0;
    if (!v1) bk1 = 0;

    const size_t NN = (size_t)N;
    const size_t NC = (size_t)C_CH * NN;

    // ---- small per-pixel outputs (coalesced) ----
    if (v0) {
        const float* cr = cand + (size_t)bk0 * CP;
        out[n0] = cr[55];                      // best_t
        out[NN + NC + n0] = 0.5f;              // best_v
        out[2 * NN + NC + n0] = 0.0f;          // beta
        out[3 * NN + NC + n0] = cr[56];        // texture
    }
    if (v1) {
        const float* cr = cand + (size_t)bk1 * CP;
        out[n1] = cr[55];
        out[NN + NC + n1] = 0.5f;
        out[2 * NN + NC + n1] = 0.0f;
        out[3 * NN + NC + n1] = cr[56];
    }

    // ---- block-coalesced writer for best_e and s_recon ----
    __shared__ int2 bkm[PIX_PER_BLK];   // {cand row offset, library row offset}
    bkm[tid]       = make_int2(bk0 * CP, (bk0 / NT) * C_CH);
    bkm[tid + BLK] = make_int2(bk1 * CP, (bk1 / NT) * C_CH);

    float lsum = (v0 ? bl0 : 0.0f) + (v1 ? bl1 : 0.0f);
    __syncthreads();

    {
        float* __restrict__ be = out + NN + (size_t)base * C_CH;
        float* __restrict__ sr = out + 4 * NN + NC + (size_t)base * C_CH;
        int p = tid / C_CH;
        int c = tid - p * C_CH;
        #pragma unroll 4
        for (int j = tid; j < PIX_PER_BLK * C_CH; j += BLK) {   // 108 iterations
            const int2 o = bkm[p];
            const float ev = library[o.y + c];   // L1-resident (1.3 KB)
            const float sv = cand[o.x + c];      // L1/L2-resident (30 KB)
            if (base + p < N) { be[j] = ev; sr[j] = sv; }
            p += 4; c += 40;
            if (c >= C_CH) { c -= C_CH; ++p; }
        }
    }

    // ---- deterministic block reduction of best_loss sum ----
    __shared__ float red[BLK];
    red[tid] = lsum;
    __syncthreads();
    #pragma unroll
    for (int s = BLK / 2; s > 0; s >>= 1) {
        if (tid < s) red[tid] += red[tid + s];
        __syncthreads();
    }
    if (tid == 0) partials[blockIdx.x] = red[0];
}

// ---------------- final reduce: objective = mean(best_loss) ----------------
__global__ __launch_bounds__(256) void hadar_reduce(
    const float* __restrict__ partials, int nb, float* __restrict__ obj_out, float invN)
{
    __shared__ float red[256];
    float s = 0.0f;
    for (int i = threadIdx.x; i < nb; i += 256) s += partials[i];
    red[threadIdx.x] = s;
    __syncthreads();
    #pragma unroll
    for (int st = 128; st > 0; st >>= 1) {
        if (threadIdx.x < st) red[threadIdx.x] += red[threadIdx.x + st];
        __syncthreads();
    }
    if (threadIdx.x == 0) *obj_out = red[0] * invN;
}

extern "C" void kernel_launch(void* const* d_in, const int* in_sizes, int n_in,
                              void* d_out, int out_size, void* d_ws, size_t ws_size,
                              hipStream_t stream)
{
    const float* s_obs    = (const float*)d_in[0];
    const float* s_sky    = (const float*)d_in[1];
    const float* s_ground = (const float*)d_in[2];
    const float* library  = (const float*)d_in[3];
    const float* wg       = (const float*)d_in[4];
    float* out = (float*)d_out;

    const int N  = in_sizes[0] / C_CH;
    const int nb = (N + PIX_PER_BLK - 1) / PIX_PER_BLK;

    float* ws       = (float*)d_ws;
    float* cand     = ws;              // NK*CP = 7680 floats
    float* partials = ws + 8192;       // nb floats

    hadar_prep<<<1, 256, 0, stream>>>(s_sky, s_ground, library, wg, cand);
    hadar_main<<<nb, BLK, 0, stream>>>(s_obs, library, cand, out, partials, N);

    const size_t NN = (size_t)N;
    float* obj_out = out + 4 * NN + 2 * (size_t)C_CH * NN;
    hadar_reduce<<<1, 256, 0, stream>>>(partials, nb, obj_out, 1.0f / (float)N);
}